// Round 14
// baseline (300.117 us; speedup 1.0000x reference)
//
#include <hip/hip_runtime.h>

namespace {

typedef unsigned short ushort_t;
typedef short s16x8 __attribute__((ext_vector_type(8)));
typedef float f32x4 __attribute__((ext_vector_type(4)));

constexpr int B_ = 2, C_ = 64, H_ = 192, W_ = 192;
constexpr int C4 = 256;
constexpr int NPIX = H_ * W_;                       // 36864
constexpr size_t NT = (size_t)B_ * C4 * NPIX;       // 18,874,368
constexpr int PB16 = NPIX / 16;                     // 2304 16-pixel strips/batch
constexpr float EPSV = 1e-20f;

__device__ __forceinline__ ushort_t f2bu(float x) {
    union { float f; unsigned u; } v; v.f = x;
    unsigned r = v.u + 0x7fffu + ((v.u >> 16) & 1u);   // RNE to bf16
    return (ushort_t)(r >> 16);
}
__device__ __forceinline__ float bu2f(ushort_t h) {
    union { unsigned u; float f; } v; v.u = ((unsigned)h) << 16;
    return v.f;
}

// ---------------- cw -> split bf16 hi/lo + per-block cw partial sums ----------
__global__ __launch_bounds__(256) void k_prep(const float* __restrict__ cw,
                                              ushort_t* __restrict__ cwH,
                                              ushort_t* __restrict__ cwL,
                                              float* __restrict__ partial) {
    __shared__ float red[256];
    int tid = threadIdx.x;
    int i = blockIdx.x * 256 + tid;   // grid 256 -> 65536
    float w = cw[i];
    ushort_t h = f2bu(w);
    cwH[i] = h;
    cwL[i] = f2bu(w - bu2f(h));
    red[tid] = w; __syncthreads();
    for (int s2 = 128; s2 > 0; s2 >>= 1) { if (tid < s2) red[tid] += red[tid + s2]; __syncthreads(); }
    if (tid == 0) partial[blockIdx.x] = red[0];
}

// ---------------- tiny final reduction: sw sum + cw partials ----------------
__global__ __launch_bounds__(256) void k_sums2(const float* __restrict__ sw,
                                               const float* __restrict__ partial,
                                               float* __restrict__ sums) {
    __shared__ float red[256];
    int tid = threadIdx.x;
    float a = 0.f;
    for (int i = tid; i < C4 * 9; i += 256) a += sw[i];
    red[tid] = a; __syncthreads();
    for (int s2 = 128; s2 > 0; s2 >>= 1) { if (tid < s2) red[tid] += red[tid + s2]; __syncthreads(); }
    if (tid == 0) sums[0] = red[0];
    __syncthreads();
    red[tid] = partial[tid]; __syncthreads();
    for (int s2 = 128; s2 > 0; s2 >>= 1) { if (tid < s2) red[tid] += red[tid + s2]; __syncthreads(); }
    if (tid == 0) sums[1] = red[0];
}

// ---------------- FUSED stage 1+2+3: conv producer -> LDS panel -> MFMA GEMM --
// Block = 16-pixel strip (pb16) x 256 outputs, 512 threads (8 waves).
// Producer: wave w owns channels c = w*8..w*8+7 and panel chunk w.
//   Per c: lanes 0..53 run stage-1 on the 3x18 halo into wave-private temp
//   (no barrier; same-wave ds order), then all 64 lanes (k=l>>4, px=l&15)
//   convolve and write split-bf16 into the panel. Divisions cancel:
//   U = (wp*cs*s + cfd*sfd)/(wp+1); X = conv(U)/sum_sw.
// One __syncthreads, then the R12-proven GEMM + transposed epilogue.
__global__ __launch_bounds__(512) void k_fused(
    const float* __restrict__ d, const float* __restrict__ cd,
    const float* __restrict__ s, const float* __restrict__ cs,
    const float* __restrict__ w_s_from_d, const float* __restrict__ w_prop,
    const float* __restrict__ sw, const float* __restrict__ sums,
    const ushort_t* __restrict__ cwH, const ushort_t* __restrict__ cwL,
    float* __restrict__ out)
{
    __shared__ ushort_t panel[8 * 2048];        // 32 KB: chunk ks = [X 1024 | Y 1024]
    __shared__ float2 temp[8][4][3][18];        // 13.8 KB, wave-private slices

    int tid  = threadIdx.x;
    int wave = tid >> 6, lane = tid & 63;
    int l15 = lane & 15, l4 = lane >> 4;

    // bijective XCD swizzle: XCD x gets pb16 in [x*288, (x+1)*288) -> L2 row reuse
    int L = blockIdx.x;
    int pb16 = (L & 7) * (PB16 / 8) + (L >> 3);
    int b = blockIdx.y;
    int hrow = pb16 / 12, w16 = pb16 - hrow * 12;   // W_/16 = 12

    float w0s    = w_s_from_d[0];
    float inv_sw = 1.f / (sums[0] + EPSV);

    // ---------------- producer ----------------
    int ry = lane / 18, rx = lane - ry * 18;        // valid for lane < 54
    #pragma unroll 1
    for (int i = 0; i < 8; ++i) {
        int c = wave * 8 + i;
        float wp  = w_prop[c];
        float ivp = 1.f / (wp + 1.f);
        float b1  = wp * ivp;

        if (lane < 54) {                            // stage-1 on 3x18 halo
            int gh = hrow - 1 + ry;
            int gw = w16 * 16 - 1 + rx;
            if ((unsigned)gh < (unsigned)H_ && (unsigned)gw < (unsigned)W_) {
                const float* dbc  = d  + (size_t)(b * C_ + c) * NPIX;
                const float* cdbc = cd + (size_t)(b * C_ + c) * NPIX;
                float mn = 0.f, cmn = 0.f, mx = 0.f, cmx = 0.f;
                if (gh >= 1 && gw >= 1) {
                    size_t q = (size_t)(gh - 1) * W_ + (gw - 1);
                    mn = dbc[q]; cmn = cdbc[q];
                }
                if (gh < H_ - 1 && gw < W_ - 1) {
                    size_t q = (size_t)(gh + 1) * W_ + (gw + 1);
                    mx = dbc[q]; cmx = cdbc[q];
                }
                float r = __fdividef(mn, mx + EPSV);
                r = fminf(fmaxf(r, 0.f), 1.f);
                float sfd = r * fmaf(w0s, r, 1.f - w0s);
                float cfd = cmn * cmx;
                float a1 = cfd * sfd * ivp;
                float c1 = cfd * ivp;
                size_t gbase = (size_t)((b * C_ + c) * 4) * NPIX + (size_t)gh * W_ + gw;
                #pragma unroll
                for (int k = 0; k < 4; ++k) {
                    float s_v  = s[gbase + (size_t)k * NPIX];
                    float cs_v = cs[gbase + (size_t)k * NPIX];
                    float t = b1 * cs_v;
                    temp[wave][k][ry][rx] = make_float2(fmaf(t, s_v, a1), t + c1);
                }
            } else {
                #pragma unroll
                for (int k = 0; k < 4; ++k) temp[wave][k][ry][rx] = make_float2(0.f, 0.f);
            }
        }
        // same-wave ds write->read ordered by lgkmcnt (compiler, same array)

        // conv: lane = (k = l4, px = l15)
        float nom = 0.f, den = 0.f;
        const float* swk = sw + (c * 4 + l4) * 9;
        #pragma unroll
        for (int dy = 0; dy < 3; ++dy)
            #pragma unroll
            for (int dx = 0; dx < 3; ++dx) {
                float2 P = temp[wave][l4][dy][l15 + dx];
                float wgt = swk[dy * 3 + dx];
                nom = fmaf(wgt, P.x, nom);
                den = fmaf(wgt, P.y, den);
            }
        float xv = nom * inv_sw;
        float yv = den * inv_sw;
        ushort_t hx = f2bu(xv), hy = f2bu(yv);
        ushort_t lx = f2bu(xv - bu2f(hx)), ly = f2bu(yv - bu2f(hy));
        ushort_t* xp = panel + wave * 2048 + i * 128 + l15 * 8;   // chunk=wave, g=i
        xp[l4]            = hx;
        xp[4 + l4]        = lx;
        xp[1024 + l4]     = hy;
        xp[1024 + 4 + l4] = ly;
    }

    __syncthreads();   // panel complete, visible to all waves

    // ---------------- GEMM (R12-proven fragment paths) ----------------
    int o0 = wave * 32;
    f32x4 accn[2] = {};
    f32x4 accd[2] = {};
    s16x8 rxx[2], ryy[2];
    s16x8 rAh[2][2], rAl[2][2];

#define MFMA __builtin_amdgcn_mfma_f32_16x16x32_bf16

#define LOADA(AB, KS) do {                                                        \
    _Pragma("unroll")                                                             \
    for (int m = 0; m < 2; ++m) {                                                 \
        size_t ro = (size_t)(o0 + m * 16 + l15) * C4 + (KS) * 32 + l4 * 8;        \
        rAh[AB][m] = *(const s16x8*)(cwH + ro);                                   \
        rAl[AB][m] = *(const s16x8*)(cwL + ro);                                   \
    } } while (0)

#define LOADB(KS) do {                                                            \
    const ushort_t* bp = panel + (KS) * 2048;                                     \
    _Pragma("unroll")                                                             \
    for (int gg = 0; gg < 2; ++gg) {                                              \
        int o_ = (l4 * 2 + gg) * 128 + l15 * 8;                                   \
        rxx[gg] = *(const s16x8*)(bp + o_);                                       \
        ryy[gg] = *(const s16x8*)(bp + 1024 + o_);                                \
    } } while (0)

#define COMPUTE(AB) do {                                                          \
    s16x8 bxh = __builtin_shufflevector(rxx[0], rxx[1], 0,1,2,3, 8,9,10,11);      \
    s16x8 bxl = __builtin_shufflevector(rxx[0], rxx[1], 4,5,6,7, 12,13,14,15);    \
    s16x8 byh = __builtin_shufflevector(ryy[0], ryy[1], 0,1,2,3, 8,9,10,11);      \
    s16x8 byl = __builtin_shufflevector(ryy[0], ryy[1], 4,5,6,7, 12,13,14,15);    \
    __builtin_amdgcn_s_setprio(1);                                                \
    _Pragma("unroll")                                                             \
    for (int m = 0; m < 2; ++m) {                                                 \
        accn[m] = MFMA(rAh[AB][m], bxh, accn[m], 0, 0, 0);                        \
        accn[m] = MFMA(rAh[AB][m], bxl, accn[m], 0, 0, 0);                        \
        accn[m] = MFMA(rAl[AB][m], bxh, accn[m], 0, 0, 0);                        \
        accd[m] = MFMA(rAh[AB][m], byh, accd[m], 0, 0, 0);                        \
        accd[m] = MFMA(rAh[AB][m], byl, accd[m], 0, 0, 0);                        \
        accd[m] = MFMA(rAl[AB][m], byh, accd[m], 0, 0, 0);                        \
    }                                                                             \
    __builtin_amdgcn_s_setprio(0); } while (0)

    LOADA(0, 0);
    LOADA(1, 1); LOADB(0); COMPUTE(0);
    LOADA(0, 2); LOADB(1); COMPUTE(1);
    LOADA(1, 3); LOADB(2); COMPUTE(0);
    LOADA(0, 4); LOADB(3); COMPUTE(1);
    LOADA(1, 5); LOADB(4); COMPUTE(0);
    LOADA(0, 6); LOADB(5); COMPUTE(1);
    LOADA(1, 7); LOADB(6); COMPUTE(0);
    LOADB(7); COMPUTE(1);

#undef COMPUTE
#undef LOADB
#undef LOADA
#undef MFMA

    // ---------------- epilogue: LDS transpose -> full-line stores ----------
    float* ts = reinterpret_cast<float*>(panel);   // 256 x 20 floats = 20,480 B
    float inv_scw = 1.f / (sums[1] + EPSV);
    __syncthreads();   // all LOADB consumers of panel finished

    #pragma unroll
    for (int pass2 = 0; pass2 < 2; ++pass2) {
        #pragma unroll
        for (int m = 0; m < 2; ++m)
            #pragma unroll
            for (int r = 0; r < 4; ++r) {
                int o = o0 + m * 16 + l4 * 4 + r;
                float nv = accn[m][r], dv = accd[m][r];
                float val = pass2 ? dv * inv_scw : nv / (dv + EPSV);
                ts[o * 20 + l15] = val;
            }
        __syncthreads();
        size_t gb = (pass2 ? NT : 0) + (size_t)b * C4 * NPIX + (size_t)pb16 * 16;
        int j4 = (tid & 3) * 4, row = tid >> 2;   // row 0..127
        #pragma unroll
        for (int sp = 0; sp < 2; ++sp) {
            int o = sp * 128 + row;
            f32x4 v = *(const f32x4*)&ts[o * 20 + j4];
            *(f32x4*)&out[gb + (size_t)o * NPIX + j4] = v;
        }
        if (pass2 == 0) __syncthreads();
    }
}

} // namespace

extern "C" void kernel_launch(void* const* d_in, const int* in_sizes, int n_in,
                              void* d_out, int out_size, void* d_ws, size_t ws_size,
                              hipStream_t stream) {
    const float* d    = (const float*)d_in[0];
    const float* cd   = (const float*)d_in[1];
    const float* s    = (const float*)d_in[2];
    const float* cs   = (const float*)d_in[3];
    const float* w_s  = (const float*)d_in[4];
    const float* wprp = (const float*)d_in[5];
    const float* cw   = (const float*)d_in[6];
    const float* sw   = (const float*)d_in[7];
    float* out = (float*)d_out;

    ushort_t* cwH = (ushort_t*)d_ws;
    ushort_t* cwL = cwH + C4 * C4;
    float* sums   = (float*)(cwL + C4 * C4);
    float* partial = sums + 2;

    k_prep<<<C4, 256, 0, stream>>>(cw, cwH, cwL, partial);
    k_sums2<<<1, 256, 0, stream>>>(sw, partial, sums);
    k_fused<<<dim3(PB16, B_), 512, 0, stream>>>(
        d, cd, s, cs, w_s, wprp, sw, sums, cwH, cwL, out);
}

// Round 15
// 229.771 us; speedup vs baseline: 1.3062x; 1.3062x over previous
//
#include <hip/hip_runtime.h>

namespace {

typedef unsigned short ushort_t;
typedef short s16x8 __attribute__((ext_vector_type(8)));
typedef float f32x4 __attribute__((ext_vector_type(4)));

constexpr int B_ = 2, C_ = 64, H_ = 192, W_ = 192;
constexpr int C4 = 256;
constexpr int NPIX = H_ * W_;                       // 36864
constexpr size_t NT = (size_t)B_ * C4 * NPIX;       // 18,874,368
constexpr int PB = NPIX / 32;                       // 1152 32-pixel blocks per batch
constexpr float EPSV = 1e-20f;
constexpr int CHUNK = 2048;                         // ushorts per tensor per k-chunk

constexpr int TILEW = 32, TILEH = 16;
constexpr int TLX = TILEW + 2;   // 34
constexpr int TLY = TILEH + 2;   // 18

__device__ __forceinline__ ushort_t f2bu(float x) {
    union { float f; unsigned u; } v; v.f = x;
    unsigned r = v.u + 0x7fffu + ((v.u >> 16) & 1u);   // RNE to bf16
    return (ushort_t)(r >> 16);
}
__device__ __forceinline__ float bu2f(ushort_t h) {
    union { unsigned u; float f; } v; v.u = ((unsigned)h) << 16;
    return v.f;
}

__device__ __forceinline__ void async_ld16(const ushort_t* g, ushort_t* l) {
    __builtin_amdgcn_global_load_lds(
        (const __attribute__((address_space(1))) unsigned int*)g,
        (__attribute__((address_space(3))) unsigned int*)l, 16, 0, 0);
}

// ---------------- cw -> split bf16 hi/lo + per-block cw partial sums ----------
__global__ __launch_bounds__(256) void k_prep(const float* __restrict__ cw,
                                              ushort_t* __restrict__ cwH,
                                              ushort_t* __restrict__ cwL,
                                              float* __restrict__ partial) {
    __shared__ float red[256];
    int tid = threadIdx.x;
    int i = blockIdx.x * 256 + tid;   // grid 256 -> 65536
    float w = cw[i];
    ushort_t h = f2bu(w);
    cwH[i] = h;
    cwL[i] = f2bu(w - bu2f(h));
    red[tid] = w; __syncthreads();
    for (int s2 = 128; s2 > 0; s2 >>= 1) { if (tid < s2) red[tid] += red[tid + s2]; __syncthreads(); }
    if (tid == 0) partial[blockIdx.x] = red[0];
}

// ---------------- tiny final reduction: sw sum + cw partials ----------------
__global__ __launch_bounds__(256) void k_sums2(const float* __restrict__ sw,
                                               const float* __restrict__ partial,
                                               float* __restrict__ sums) {
    __shared__ float red[256];
    int tid = threadIdx.x;
    float a = 0.f;
    for (int i = tid; i < C4 * 9; i += 256) a += sw[i];
    red[tid] = a; __syncthreads();
    for (int s2 = 128; s2 > 0; s2 >>= 1) { if (tid < s2) red[tid] += red[tid + s2]; __syncthreads(); }
    if (tid == 0) sums[0] = red[0];
    __syncthreads();
    red[tid] = partial[tid]; __syncthreads();
    for (int s2 = 128; s2 > 0; s2 >>= 1) { if (tid < s2) red[tid] += red[tid + s2]; __syncthreads(); }
    if (tid == 0) sums[1] = red[0];
}

// ---------------- fused stage 1 + stage 2 (depthwise conv) ----------------
// R11 structure (ONE barrier, float2-interleaved u/v in LDS) with a 32x16
// spatial tile: LDS 19.58 KB -> 8 blocks/CU (VGPR ~52 allows 32 waves/CU).
// Divisions cancel: U = cs_prop*s_prop = (wp*cs*s + cfd*sfd)/(wp+1),
// X = cs_spatial*s_spatial = conv(U)/sum_sw (den/(den+1e-20) == 1).
// Emits XP/YP packed split-bf16: element (b, pb, g, pix32, j) at
// ((b*PB+pb)*64 + g)*256 + pix*8 + j ; j = [hi of k=0..3 | lo of k=0..3].
__global__ __launch_bounds__(256) void k_stage12(
    const float* __restrict__ d, const float* __restrict__ cd,
    const float* __restrict__ s, const float* __restrict__ cs,
    const float* __restrict__ w_s_from_d, const float* __restrict__ w_prop,
    const float* __restrict__ sw, const float* __restrict__ sums,
    ushort_t* __restrict__ XP, ushort_t* __restrict__ YP)
{
    __shared__ float2 uv_[4][TLY][TLX];   // 4*18*34*8 = 19,584 B (u=.x, v=.y)
    __shared__ float swl[4][9];

    int tid = threadIdx.x;
    int blk = blockIdx.x;
    constexpr int TX = W_ / TILEW, TY = H_ / TILEH;   // 6 x 12
    int tx0 = blk % TX; blk /= TX;
    int ty0 = blk % TY; blk /= TY;
    int c = blk % C_;
    int b = blk / C_;
    int h0 = ty0 * TILEH, w0 = tx0 * TILEW;

    const float* dbc  = d  + (size_t)(b * C_ + c) * NPIX;
    const float* cdbc = cd + (size_t)(b * C_ + c) * NPIX;

    if (tid < 36) swl[tid / 9][tid % 9] = sw[(c * 4 + tid / 9) * 9 + tid % 9];

    float w0s = w_s_from_d[0];
    float wp  = w_prop[c];
    float inv_wp1 = 1.f / (wp + 1.f);
    float inv_sw  = 1.f / (sums[0] + EPSV);
    float b1 = wp * inv_wp1;

    // fill: stage 1 on the halo-1 grid (18x34); only direction 0 survives the
    // reference's argmax over identical stacked copies.
    for (int i = tid; i < TLY * TLX; i += 256) {
        int y = i / TLX, x = i - y * TLX;
        int gh = h0 - 1 + y, gw = w0 - 1 + x;
        if ((unsigned)gh < (unsigned)H_ && (unsigned)gw < (unsigned)W_) {
            float mn = 0.f, cmn = 0.f, mx = 0.f, cmx = 0.f;
            if (gh >= 1 && gw >= 1) {
                size_t q = (size_t)(gh - 1) * W_ + (gw - 1);
                mn = dbc[q]; cmn = cdbc[q];
            }
            if (gh < H_ - 1 && gw < W_ - 1) {
                size_t q = (size_t)(gh + 1) * W_ + (gw + 1);
                mx = dbc[q]; cmx = cdbc[q];
            }
            float r = __fdividef(mn, mx + EPSV);
            r = fminf(fmaxf(r, 0.f), 1.f);
            float sfd = r * fmaf(w0s, r, 1.f - w0s);
            float cfd = cmn * cmx;
            float a1 = cfd * sfd * inv_wp1;
            float c1 = cfd * inv_wp1;
            size_t gbase = (size_t)((b * C_ + c) * 4) * NPIX + (size_t)gh * W_ + gw;
            #pragma unroll
            for (int k = 0; k < 4; ++k) {
                float s_v  = s[gbase + (size_t)k * NPIX];
                float cs_v = cs[gbase + (size_t)k * NPIX];
                float t = b1 * cs_v;
                uv_[k][y][x] = make_float2(fmaf(t, s_v, a1), t + c1);
            }
        } else {
            #pragma unroll
            for (int k = 0; k < 4; ++k) uv_[k][y][x] = make_float2(0.f, 0.f);
        }
    }
    __syncthreads();

    // conv: per-pixel, one b64 read per tap; thread covers 2 pixels
    #pragma unroll
    for (int p = 0; p < 2; ++p) {
        int i = p * 256 + tid;
        int ty = i >> 5, tx = i & 31;
        s16x8 kx, ky;
        #pragma unroll
        for (int k = 0; k < 4; ++k) {
            float nom = 0.f, den = 0.f;
            #pragma unroll
            for (int dy = 0; dy < 3; ++dy)
                #pragma unroll
                for (int dx = 0; dx < 3; ++dx) {
                    float2 P = uv_[k][ty + dy][tx + dx];
                    float wgt = swl[k][dy * 3 + dx];
                    nom = fmaf(wgt, P.x, nom);
                    den = fmaf(wgt, P.y, den);
                }
            float xv = nom * inv_sw;
            float yv = den * inv_sw;
            ushort_t hx = f2bu(xv);
            ushort_t hy = f2bu(yv);
            kx[k]     = (short)hx;
            kx[4 + k] = (short)f2bu(xv - bu2f(hx));
            ky[k]     = (short)hy;
            ky[4 + k] = (short)f2bu(yv - bu2f(hy));
        }
        int pb = (h0 + ty) * (W_ / 32) + (w0 >> 5);
        size_t base = ((size_t)(b * PB + pb) * 64 + c) * 256 + (size_t)tx * 8;
        *(s16x8*)(XP + base) = kx;
        *(s16x8*)(YP + base) = ky;
    }
}

// ---------------- stage 3: split-bf16 MFMA GEMM, monolithic LDS stage --------
// R11-proven: 512 threads (8 waves), tile 256 o x 32 pix, whole 64 KB B-panel
// staged via global_load_lds, 2-barrier counted-vmcnt schedule, LDS-transpose
// epilogue for full-line stores.
__global__ __launch_bounds__(512, 4) void k_stage3(
    const ushort_t* __restrict__ XP, const ushort_t* __restrict__ YP,
    const ushort_t* __restrict__ cwH, const ushort_t* __restrict__ cwL,
    const float* __restrict__ sums, float* __restrict__ out)
{
    __shared__ ushort_t stg[8 * 2 * CHUNK];   // 64 KiB: 8 chunks x [X 4KB | Y 4KB]

    int tid  = threadIdx.x;
    int wave = tid >> 6, lane = tid & 63;
    int l15 = lane & 15, l4 = lane >> 4;
    int pb = blockIdx.x;
    int b  = blockIdx.y;
    int o0 = wave * 32;

    size_t xbase = (size_t)(b * PB + pb) * 16384;   // ushorts: 64 g * 256
    const ushort_t* gsrc = ((wave & 4) ? YP : XP) + xbase
                         + (size_t)(wave & 3) * 512 + (size_t)lane * 8;
    ushort_t* lbase = stg + ((wave & 4) ? CHUNK : 0) + (wave & 3) * 512;

    f32x4 accn[2][2] = {};
    f32x4 accd[2][2] = {};
    s16x8 rx[2][2], ry[2][2];
    s16x8 rAh[2][2], rAl[2][2];

#define MFMA __builtin_amdgcn_mfma_f32_16x16x32_bf16

#define STAGE(KS) async_ld16(gsrc + (size_t)(KS) * 2048, lbase + (KS) * (2 * CHUNK))

#define LOADA(AB, KS) do {                                                        \
    _Pragma("unroll")                                                             \
    for (int m = 0; m < 2; ++m) {                                                 \
        size_t ro = (size_t)(o0 + m * 16 + l15) * C4 + (KS) * 32 + l4 * 8;        \
        rAh[AB][m] = *(const s16x8*)(cwH + ro);                                   \
        rAl[AB][m] = *(const s16x8*)(cwL + ro);                                   \
    } } while (0)

#define LOADB(KS) do {                                                            \
    const ushort_t* bp = stg + (KS) * (2 * CHUNK);                                \
    _Pragma("unroll")                                                             \
    for (int n = 0; n < 2; ++n)                                                   \
        _Pragma("unroll")                                                         \
        for (int gg = 0; gg < 2; ++gg) {                                          \
            int o_ = (l4 * 2 + gg) * 256 + (n * 16 + l15) * 8;                    \
            rx[n][gg] = *(const s16x8*)(bp + o_);                                 \
            ry[n][gg] = *(const s16x8*)(bp + CHUNK + o_);                         \
        } } while (0)

#define COMPUTE(AB) do {                                                          \
    _Pragma("unroll")                                                             \
    for (int n = 0; n < 2; ++n) {                                                 \
        s16x8 bxh = __builtin_shufflevector(rx[n][0], rx[n][1], 0,1,2,3, 8,9,10,11);   \
        s16x8 bxl = __builtin_shufflevector(rx[n][0], rx[n][1], 4,5,6,7, 12,13,14,15); \
        s16x8 byh = __builtin_shufflevector(ry[n][0], ry[n][1], 0,1,2,3, 8,9,10,11);   \
        s16x8 byl = __builtin_shufflevector(ry[n][0], ry[n][1], 4,5,6,7, 12,13,14,15); \
        _Pragma("unroll")                                                         \
        for (int m = 0; m < 2; ++m) {                                             \
            accn[m][n] = MFMA(rAh[AB][m], bxh, accn[m][n], 0, 0, 0);              \
            accn[m][n] = MFMA(rAh[AB][m], bxl, accn[m][n], 0, 0, 0);              \
            accn[m][n] = MFMA(rAl[AB][m], bxh, accn[m][n], 0, 0, 0);              \
            accd[m][n] = MFMA(rAh[AB][m], byh, accd[m][n], 0, 0, 0);              \
            accd[m][n] = MFMA(rAh[AB][m], byl, accd[m][n], 0, 0, 0);              \
            accd[m][n] = MFMA(rAl[AB][m], byh, accd[m][n], 0, 0, 0);              \
        } } } while (0)

    // prologue: stage ALL 8 chunks (8 VMEM), then A0 (4 VMEM)
    STAGE(0); STAGE(1); STAGE(2); STAGE(3);
    STAGE(4); STAGE(5); STAGE(6); STAGE(7);
    __builtin_amdgcn_sched_barrier(0);
    LOADA(0, 0);
    __builtin_amdgcn_sched_barrier(0);

    // wait: own S0..S3 retired (12 issued, <=8 outstanding -> >=4 retired)
    asm volatile("s_waitcnt vmcnt(8)" ::: "memory");
    __builtin_amdgcn_s_barrier();
    __builtin_amdgcn_sched_barrier(0);

    LOADA(1, 1); LOADB(0); COMPUTE(0);
    LOADA(0, 2); LOADB(1); COMPUTE(1);
    LOADA(1, 3); LOADB(2); COMPUTE(0);
    LOADA(0, 4); LOADB(3); COMPUTE(1);

    // wait: own S0..S7 retired (28 issued by now, <=20 outstanding -> >=8 retired)
    asm volatile("s_waitcnt vmcnt(20)" ::: "memory");
    __builtin_amdgcn_s_barrier();
    __builtin_amdgcn_sched_barrier(0);

    LOADA(1, 5); LOADB(4); COMPUTE(0);
    LOADA(0, 6); LOADB(5); COMPUTE(1);
    LOADA(1, 7); LOADB(6); COMPUTE(0);
    LOADB(7); COMPUTE(1);

#undef COMPUTE
#undef LOADB
#undef LOADA
#undef STAGE
#undef MFMA

    // -------- epilogue: LDS transpose -> full-line coalesced stores --------
    float* ts = reinterpret_cast<float*>(stg);   // 256 x 36 floats = 36,864 B
    float inv_scw = 1.f / (sums[1] + EPSV);
    __syncthreads();   // all LOADB consumers of stg finished

    #pragma unroll
    for (int pass2 = 0; pass2 < 2; ++pass2) {
        #pragma unroll
        for (int m = 0; m < 2; ++m)
            #pragma unroll
            for (int n = 0; n < 2; ++n)
                #pragma unroll
                for (int r = 0; r < 4; ++r) {
                    int o = o0 + m * 16 + l4 * 4 + r;
                    float nv = accn[m][n][r], dv = accd[m][n][r];
                    float val = pass2 ? dv * inv_scw : nv / (dv + EPSV);
                    ts[o * 36 + n * 16 + l15] = val;
                }
        __syncthreads();
        size_t gb = (pass2 ? NT : 0) + (size_t)b * C4 * NPIX + (size_t)pb * 32;
        int oo = tid >> 3, j = tid & 7;
        #pragma unroll
        for (int pass = 0; pass < 4; ++pass) {
            int o = pass * 64 + oo;
            f32x4 v = *(const f32x4*)&ts[o * 36 + j * 4];
            *(f32x4*)&out[gb + (size_t)o * NPIX + j * 4] = v;
        }
        if (pass2 == 0) __syncthreads();
    }
}

} // namespace

extern "C" void kernel_launch(void* const* d_in, const int* in_sizes, int n_in,
                              void* d_out, int out_size, void* d_ws, size_t ws_size,
                              hipStream_t stream) {
    const float* d    = (const float*)d_in[0];
    const float* cd   = (const float*)d_in[1];
    const float* s    = (const float*)d_in[2];
    const float* cs   = (const float*)d_in[3];
    const float* w_s  = (const float*)d_in[4];
    const float* wprp = (const float*)d_in[5];
    const float* cw   = (const float*)d_in[6];
    const float* sw   = (const float*)d_in[7];
    float* out = (float*)d_out;

    ushort_t* XP  = (ushort_t*)d_ws;
    ushort_t* YP  = XP + 2 * NT;
    ushort_t* cwH = YP + 2 * NT;
    ushort_t* cwL = cwH + C4 * C4;
    float* sums   = (float*)(cwL + C4 * C4);
    float* partial = sums + 2;

    k_prep<<<C4, 256, 0, stream>>>(cw, cwH, cwL, partial);
    k_sums2<<<1, 256, 0, stream>>>(sw, partial, sums);
    // 6 x 12 tiles per (b,c) = 9216 blocks
    k_stage12<<<dim3(B_ * C_ * (H_ / TILEH) * (W_ / TILEW)), 256, 0, stream>>>(
        d, cd, s, cs, w_s, wprp, sw, sums, XP, YP);
    k_stage3<<<dim3(PB, B_), 512, 0, stream>>>(XP, YP, cwH, cwL, sums, out);
}